// Round 2
// baseline (243.635 us; speedup 1.0000x reference)
//
#include <hip/hip_runtime.h>

// QWTForward: reference's filtering is exactly x * sum(h); downsample is
// linear; so all 16 output blocks are (S_A*S_B) * D, D = bicubic-down2(image).
// One fused memory-bound kernel: read 50 MB, write 201 MB.
//
// R2 changes vs R1:
//  - halo columns via __shfl from neighbor lanes (kills 8 strided scalar
//    loads/thread; w4 == lane id because block=256 and w4 = idx & 63)
//  - per-wave rotation of the 16 (t,cb) store targets (avoid all 16 streams
//    of a wave camping on one channel group: strides are 768 KiB / 48 MiB
//    with identical low address bits)
//  - nontemporal float4 stores (201 MB streaming output, zero reuse)

#define BW0 -0.09375f
#define BW1  0.59375f
#define BW2  0.59375f
#define BW3 -0.09375f

#define H_IN  512
#define W_IN  512
#define H_OUT 256
#define W_OUT 256
#define PLANE_OUT (H_OUT * W_OUT)           // 65536
#define TENSOR_STRIDE (16 * 12 * PLANE_OUT) // floats per output tensor

typedef float f4 __attribute__((ext_vector_type(4)));

__global__ __launch_bounds__(256) void qwt_fused_kernel(
    const float* __restrict__ img,
    const float* __restrict__ gl, const float* __restrict__ gh,
    const float* __restrict__ fl, const float* __restrict__ fh,
    float* __restrict__ out)
{
    __shared__ float s_scale[16];

    const int tid = threadIdx.x;

    // ---- wave 0: filter sums + 16 scale products -> LDS ----
    if (tid < 64) {
        float vgl = 0.f, vgh = 0.f, vfl = 0.f, vfh = 0.f;
        if (tid < 30) { vgl = gl[tid]; vgh = gh[tid]; vfl = fl[tid]; vfh = fh[tid]; }
        #pragma unroll
        for (int m = 32; m >= 1; m >>= 1) {
            vgl += __shfl_xor(vgl, m);
            vgh += __shfl_xor(vgh, m);
            vfl += __shfl_xor(vfl, m);
            vfh += __shfl_xor(vfh, m);
        }
        if (tid < 16) {
            const int t = tid >> 2, cb = tid & 3;
            const float A = (t < 2) ? ((cb & 1) ? vfl : vgl)
                                    : ((cb & 1) ? vfh : vgh);
            const float B = (t & 1) ? ((cb < 2) ? vgh : vfh)
                                    : ((cb < 2) ? vgl : vfl);
            s_scale[tid] = A * B;
        }
    }
    __syncthreads();

    // ---- each thread: one float4 of D ----
    // idx -> 64 w-groups x 256 h x 48 planes
    const int idx = blockIdx.x * 256 + tid;
    const int w4 = idx & 63;            // == lane id (block=256, 64 | 256)
    const int h  = (idx >> 6) & 255;
    const int bc = idx >> 14;           // b*3 + c, 0..47
    const int c  = bc % 3;
    const int b  = bc / 3;

    const float* plane = img + (size_t)bc * (H_IN * W_IN);

    int r[4];
    #pragma unroll
    for (int i = 0; i < 4; ++i) {
        int rr = 2 * h - 1 + i;
        r[i] = rr < 0 ? 0 : (rr > H_IN - 1 ? H_IN - 1 : rr);
    }

    const int cbase = w4 * 8;

    float hv[4][4];
    #pragma unroll
    for (int i = 0; i < 4; ++i) {
        const float* rowp = plane + (size_t)r[i] * W_IN;
        const float4 a  = *(const float4*)(rowp + cbase);
        const float4 b4 = *(const float4*)(rowp + cbase + 4);
        const float v1 = a.x,  v2 = a.y,  v3 = a.z,  v4 = a.w;
        const float v5 = b4.x, v6 = b4.y, v7 = b4.z, v8 = b4.w;
        // halo from neighbor lanes (col 8*w4-1 is prev lane's v8; col 8*w4+8
        // is next lane's v1), clamped at the image edge
        float v0 = __shfl_up(v8, 1);
        float v9 = __shfl_down(v1, 1);
        if (w4 == 0)  v0 = v1;   // col -1  -> clamp to col 0
        if (w4 == 63) v9 = v8;   // col 512 -> clamp to col 511
        hv[i][0] = BW0 * v0 + BW1 * v1 + BW2 * v2 + BW3 * v3;
        hv[i][1] = BW0 * v2 + BW1 * v3 + BW2 * v4 + BW3 * v5;
        hv[i][2] = BW0 * v4 + BW1 * v5 + BW2 * v6 + BW3 * v7;
        hv[i][3] = BW0 * v6 + BW1 * v7 + BW2 * v8 + BW3 * v9;
    }

    float d0 = BW0 * hv[0][0] + BW1 * hv[1][0] + BW2 * hv[2][0] + BW3 * hv[3][0];
    float d1 = BW0 * hv[0][1] + BW1 * hv[1][1] + BW2 * hv[2][1] + BW3 * hv[3][1];
    float d2 = BW0 * hv[0][2] + BW1 * hv[1][2] + BW2 * hv[2][2] + BW3 * hv[3][2];
    float d3 = BW0 * hv[0][3] + BW1 * hv[1][3] + BW2 * hv[2][3] + BW3 * hv[3][3];

    // ---- 16 coalesced nontemporal float4 stores, wave-rotated order ----
    const size_t obase = (size_t)b * (12 * PLANE_OUT)
                       + (size_t)c * PLANE_OUT
                       + (size_t)h * W_OUT
                       + (size_t)(w4 * 4);
    const int rot = (blockIdx.x + (tid >> 6)) & 15;
    #pragma unroll
    for (int kk = 0; kk < 16; ++kk) {
        const int k = (kk + rot) & 15;
        const float s = s_scale[k];
        f4 o;
        o.x = d0 * s; o.y = d1 * s; o.z = d2 * s; o.w = d3 * s;
        float* p = out + (size_t)(k >> 2) * TENSOR_STRIDE
                       + obase
                       + (size_t)(k & 3) * (3 * PLANE_OUT);
        __builtin_nontemporal_store(o, (f4*)p);
    }
}

extern "C" void kernel_launch(void* const* d_in, const int* in_sizes, int n_in,
                              void* d_out, int out_size, void* d_ws, size_t ws_size,
                              hipStream_t stream) {
    const float* img = (const float*)d_in[0];
    const float* gl  = (const float*)d_in[1];
    const float* gh  = (const float*)d_in[2];
    const float* fl  = (const float*)d_in[3];
    const float* fh  = (const float*)d_in[4];
    float* out = (float*)d_out;

    const int threads = 256;
    const int blocks  = (16 * 3 * 256 * 256 / 4) / threads; // 3072
    qwt_fused_kernel<<<blocks, threads, 0, stream>>>(img, gl, gh, fl, fh, out);
}